// Round 2
// baseline (1033.980 us; speedup 1.0000x reference)
//
#include <hip/hip_runtime.h>
#include <hip/hip_bf16.h>

typedef __attribute__((ext_vector_type(8))) short short8;
typedef __attribute__((ext_vector_type(4))) float floatx4;

#define LDP 72    // LDS staging pitch (ushorts) for 64-wide K tiles: 144B rows, 16B-aligned, ~2-way banks
#define TP  136   // LDS pitch (ushorts) for 128-wide tiles: 272B rows, 16B-aligned

#define ATTN_OFF ((size_t)16 * 2048 * 512)   // out is first in d_out, attn second

__device__ __forceinline__ unsigned short f2bf(float f) {
    union { __hip_bfloat16 h; unsigned short u; } cv;
    cv.h = __float2bfloat16(f);
    return cv.u;
}

__device__ __forceinline__ uint2 f4_to_bf4(float x, float y, float z, float w) {
    uint2 r;
    r.x = (unsigned)f2bf(x) | ((unsigned)f2bf(y) << 16);
    r.y = (unsigned)f2bf(z) | ((unsigned)f2bf(w) << 16);
    return r;
}

__device__ __forceinline__ short8 f8_to_bf8(float4 a, float4 b) {
    union { uint4 u; short8 s; } cv;
    uint2 lo = f4_to_bf4(a.x, a.y, a.z, a.w);
    uint2 hi = f4_to_bf4(b.x, b.y, b.z, b.w);
    cv.u.x = lo.x; cv.u.y = lo.y; cv.u.z = hi.x; cv.u.w = hi.y;
    return cv.s;
}

// ---------------------------------------------------------------------------
// K1: projections.  out[n,e] = (sum_d x[n,d] * W[e,d]) * c   (NT GEMM, K=512)
// mat 0: qp  (c = 1/sqrt(512) * 512^-0.5 = 1/512, attn scale folded in)
// mat 1: kp  (c = 1/sqrt(512))
// mat 2: vpT (c = 1/sqrt(512)), stored K-chunk-tiled [b][tok>>5][e][tok&31]
//        so out_kernel's B-fragment loads are 1KB-contiguous per wave instr.
// ---------------------------------------------------------------------------
__global__ __launch_bounds__(256, 2)
void proj_kernel(const float* __restrict__ q, const float* __restrict__ k,
                 const float* __restrict__ v, const float* __restrict__ wq,
                 const float* __restrict__ wk, const float* __restrict__ wv,
                 unsigned short* __restrict__ qp, unsigned short* __restrict__ kp,
                 unsigned short* __restrict__ vpT)
{
    const int mat = blockIdx.z;
    const float* __restrict__ x = (mat == 0) ? q : (mat == 1) ? k : v;
    const float* __restrict__ w = (mat == 0) ? wq : (mat == 1) ? wk : wv;
    const float scale = (mat == 0) ? (1.0f / 512.0f) : 0.044194173824159216f;

    const int m0 = blockIdx.x * 128;   // token row (global over 32768)
    const int n0 = blockIdx.y * 128;   // e col

    __shared__ __align__(16) unsigned short sm[2 * 128 * LDP];   // 36864 B
    unsigned short* lds_a = sm;
    unsigned short* lds_b = sm + 128 * LDP;
    unsigned short* lds_t = sm;        // epilogue transpose buf, 128*TP = 17408 <= 18432

    const int t = threadIdx.x;
    const int wave = t >> 6, ln = t & 15, qd = (t >> 4) & 3;
    const int wm = wave >> 1, wn = wave & 1;

    floatx4 acc[4][4];
    for (int mi = 0; mi < 4; ++mi)
        for (int ni = 0; ni < 4; ++ni)
            acc[mi][ni] = (floatx4){0.f, 0.f, 0.f, 0.f};

    for (int kb = 0; kb < 512; kb += 64) {
        for (int i = 0; i < 8; ++i) {
            int lin = t + 256 * i;
            int row = lin >> 4, c4 = lin & 15;
            const float4 a4 = *(const float4*)&x[(size_t)(m0 + row) * 512 + kb + c4 * 4];
            *(uint2*)&lds_a[row * LDP + c4 * 4] = f4_to_bf4(a4.x, a4.y, a4.z, a4.w);
            const float4 b4 = *(const float4*)&w[(size_t)(n0 + row) * 512 + kb + c4 * 4];
            *(uint2*)&lds_b[row * LDP + c4 * 4] = f4_to_bf4(b4.x, b4.y, b4.z, b4.w);
        }
        __syncthreads();
        for (int kk = 0; kk < 2; ++kk) {
            short8 af[4], bg[4];
            for (int mi = 0; mi < 4; ++mi)
                af[mi] = *(const short8*)&lds_a[(wm * 64 + mi * 16 + ln) * LDP + kk * 32 + qd * 8];
            for (int ni = 0; ni < 4; ++ni)
                bg[ni] = *(const short8*)&lds_b[(wn * 64 + ni * 16 + ln) * LDP + kk * 32 + qd * 8];
            for (int mi = 0; mi < 4; ++mi)
                for (int ni = 0; ni < 4; ++ni)
                    acc[mi][ni] = __builtin_amdgcn_mfma_f32_16x16x32_bf16(
                        af[mi], bg[ni], acc[mi][ni], 0, 0, 0);
        }
        __syncthreads();
    }

    // epilogue: repack tile through LDS for coalesced 16B bf16 stores.
    // C/D layout: col = lane&15, row = quad*4 + reg  [m89/m91]
    for (int mi = 0; mi < 4; ++mi)
        for (int ni = 0; ni < 4; ++ni)
            for (int r = 0; r < 4; ++r) {
                float val = acc[mi][ni][r] * scale;
                int row = wm * 64 + mi * 16 + qd * 4 + r;
                int col = wn * 64 + ni * 16 + ln;
                if (mat == 2) lds_t[col * TP + row] = f2bf(val);   // [e][tok] for vpT
                else          lds_t[row * TP + col] = f2bf(val);
            }
    __syncthreads();
    if (mat < 2) {
        unsigned short* dst = (mat == 0) ? qp : kp;
        for (int i = 0; i < 8; ++i) {
            int lin = t + 256 * i;
            int row = lin >> 4, c8 = lin & 15;
            *(uint4*)&dst[(size_t)(m0 + row) * 512 + n0 + c8 * 8] =
                *(const uint4*)&lds_t[row * TP + c8 * 8];
        }
    } else {
        // vpT layout: elem (b, e, tok) at b*1048576 + (tok>>5)*16384 + e*32 + (tok&31)
        int b = m0 >> 11;
        int tloc = m0 & 2047;
        for (int i = 0; i < 8; ++i) {
            int lin = t + 256 * i;
            int row = lin >> 4, c8 = lin & 15;   // row = e-local, toks = tloc + c8*8 ..+8
            int tok = tloc + c8 * 8;
            *(uint4*)&vpT[(size_t)b * 1048576 + (size_t)(tok >> 5) * 16384
                          + (size_t)(n0 + row) * 32 + (tok & 31)] =
                *(const uint4*)&lds_t[row * TP + c8 * 8];
        }
    }
}

// ---------------------------------------------------------------------------
// K2: dots. p = exp(qp · kp^T) written unnormalized (fp32) into d_out's attn
// region; per-row sums accumulated into lsum via shuffle + LDS + global atomic.
// No max-subtraction: dots ~ N(0,1), max ~5.8, exp fits fp32 easily.
// ---------------------------------------------------------------------------
__global__ __launch_bounds__(256, 2)
void dots_kernel(const unsigned short* __restrict__ qp, const unsigned short* __restrict__ kp,
                 float* __restrict__ attn, float* __restrict__ lsum)
{
    const int b = blockIdx.z;
    const int row0 = blockIdx.y * 128;
    const int col0 = blockIdx.x * 128;

    __shared__ __align__(16) unsigned short sm[2 * 128 * LDP];
    unsigned short* lds_a = sm;
    unsigned short* lds_b = sm + 128 * LDP;
    __shared__ float lds_l[128];

    const int t = threadIdx.x;
    const int wave = t >> 6, ln = t & 15, qd = (t >> 4) & 3;
    const int wm = wave >> 1, wn = wave & 1;

    if (t < 128) lds_l[t] = 0.f;

    const unsigned short* arow = qp + (size_t)(b * 2048 + row0) * 512;
    const unsigned short* brow = kp + (size_t)(b * 2048 + col0) * 512;

    floatx4 acc[4][4];
    for (int mi = 0; mi < 4; ++mi)
        for (int ni = 0; ni < 4; ++ni)
            acc[mi][ni] = (floatx4){0.f, 0.f, 0.f, 0.f};

    for (int kb = 0; kb < 512; kb += 64) {
        for (int i = 0; i < 4; ++i) {
            int lin = t + 256 * i;
            int row = lin >> 3, c8 = lin & 7;
            *(uint4*)&lds_a[row * LDP + c8 * 8] = *(const uint4*)&arow[(size_t)row * 512 + kb + c8 * 8];
            *(uint4*)&lds_b[row * LDP + c8 * 8] = *(const uint4*)&brow[(size_t)row * 512 + kb + c8 * 8];
        }
        __syncthreads();
        for (int kk = 0; kk < 2; ++kk) {
            short8 af[4], bg[4];
            for (int mi = 0; mi < 4; ++mi)
                af[mi] = *(const short8*)&lds_a[(wm * 64 + mi * 16 + ln) * LDP + kk * 32 + qd * 8];
            for (int ni = 0; ni < 4; ++ni)
                bg[ni] = *(const short8*)&lds_b[(wn * 64 + ni * 16 + ln) * LDP + kk * 32 + qd * 8];
            for (int mi = 0; mi < 4; ++mi)
                for (int ni = 0; ni < 4; ++ni)
                    acc[mi][ni] = __builtin_amdgcn_mfma_f32_16x16x32_bf16(
                        af[mi], bg[ni], acc[mi][ni], 0, 0, 0);
        }
        __syncthreads();
    }

    float* attnb = attn + (size_t)(b * 2048 + row0) * 2048 + col0;
    for (int mi = 0; mi < 4; ++mi) {
        float s[4] = {0.f, 0.f, 0.f, 0.f};
        for (int ni = 0; ni < 4; ++ni) {
            int colL = wn * 64 + ni * 16 + ln;
            for (int r = 0; r < 4; ++r) {
                float p = __expf(acc[mi][ni][r]);
                int rowL = wm * 64 + mi * 16 + qd * 4 + r;
                attnb[(size_t)rowL * 2048 + colL] = p;
                s[r] += p;
            }
        }
        // sum over the 16 lanes holding this row's 16 columns (xor within quad)
        for (int r = 0; r < 4; ++r) {
            float vv = s[r];
            vv += __shfl_xor(vv, 1);
            vv += __shfl_xor(vv, 2);
            vv += __shfl_xor(vv, 4);
            vv += __shfl_xor(vv, 8);
            if (ln == 0) atomicAdd(&lds_l[wm * 64 + mi * 16 + qd * 4 + r], vv);
        }
    }
    __syncthreads();
    if (t < 128) atomicAdd(&lsum[b * 2048 + row0 + t], lds_l[t]);
}

// ---------------------------------------------------------------------------
// K3 v4: barrier-free, LDS-free streaming PV GEMM.
// Block = 128 rows x 512 cols, 8 waves; wave w exclusively owns rows w*16..+16
// (acc[1][32] = 128 f32 -> AGPRs). Since each wave is the sole reader AND
// writer of its P rows, the in-place normalize (attn = P*il) is race-free in
// program order: NO __syncthreads anywhere. Per iter (K chunk of 32):
//   prefetch next P chunk | af = bf16(P*il) | store attn = P*il (in place)
//   | 32 bg loads (1KB contiguous each, L2-hot vpT tiles) | 32 MFMA.
// No barrier ever drains vmcnt -> loads stream across iterations; HBM MLP is
// bounded only by vmcnt depth, not by the block-wide staging chain.
// ---------------------------------------------------------------------------
__global__ __launch_bounds__(512, 2)
void out_kernel(const unsigned short* __restrict__ vpT, float* __restrict__ attn,
                const float* __restrict__ lsum, float* __restrict__ out)
{
    const int b  = blockIdx.x;          // batch on .x -> XCD = b%8 (vpT L2 locality)
    const int r0 = blockIdx.y * 128;

    const int t = threadIdx.x;
    const int w = t >> 6, ln = t & 15, qd = (t >> 4) & 3;

    const int row = r0 + w * 16 + ln;           // lane-private P/attn row
    const float il = 1.0f / lsum[b * 2048 + row];

    float* prow = attn + ((size_t)b * 2048 + row) * 2048;
    const unsigned short* vb = vpT + (size_t)b * 1048576;

    floatx4 acc[32];
    #pragma unroll
    for (int ni = 0; ni < 32; ++ni)
        acc[ni] = (floatx4){0.f, 0.f, 0.f, 0.f};

    // prologue: first P chunk (cols qd*8 .. +8 of this lane's row)
    float4 a0 = *(const float4*)(prow + qd * 8);
    float4 a1 = *(const float4*)(prow + qd * 8 + 4);

    for (int i = 0; i < 64; ++i) {
        const int kc = i * 32;

        // prefetch next P chunk first (HBM/L3) — flies during this iter's MFMAs
        float4 n0, n1;
        if (i < 63) {
            n0 = *(const float4*)(prow + kc + 32 + qd * 8);
            n1 = *(const float4*)(prow + kc + 36 + qd * 8);
        }

        // normalize, write back in place (lane-private bytes), build A fragment
        a0.x *= il; a0.y *= il; a0.z *= il; a0.w *= il;
        a1.x *= il; a1.y *= il; a1.z *= il; a1.w *= il;
        *(float4*)(prow + kc + qd * 8)     = a0;   // final attn
        *(float4*)(prow + kc + qd * 8 + 4) = a1;
        short8 af = f8_to_bf8(a0, a1);

        // B fragments: vpT K-chunk tile, 1KB contiguous per wave instruction
        const unsigned short* vk = vb + (size_t)i * 16384;
        #pragma unroll
        for (int g = 0; g < 8; ++g) {
            short8 b0 = *(const short8*)&vk[((g * 4 + 0) * 16 + ln) * 32 + qd * 8];
            short8 b1 = *(const short8*)&vk[((g * 4 + 1) * 16 + ln) * 32 + qd * 8];
            short8 b2 = *(const short8*)&vk[((g * 4 + 2) * 16 + ln) * 32 + qd * 8];
            short8 b3 = *(const short8*)&vk[((g * 4 + 3) * 16 + ln) * 32 + qd * 8];
            acc[g * 4 + 0] = __builtin_amdgcn_mfma_f32_16x16x32_bf16(af, b0, acc[g * 4 + 0], 0, 0, 0);
            acc[g * 4 + 1] = __builtin_amdgcn_mfma_f32_16x16x32_bf16(af, b1, acc[g * 4 + 1], 0, 0, 0);
            acc[g * 4 + 2] = __builtin_amdgcn_mfma_f32_16x16x32_bf16(af, b2, acc[g * 4 + 2], 0, 0, 0);
            acc[g * 4 + 3] = __builtin_amdgcn_mfma_f32_16x16x32_bf16(af, b3, acc[g * 4 + 3], 0, 0, 0);
        }

        if (i < 63) { a0 = n0; a1 = n1; }
    }

    // epilogue: acc is already the normalized output (af was normalized).
    // C/D layout: col = lane&15 = ln, row = qd*4 + r.
    float* outb = out + ((size_t)b * 2048 + r0 + w * 16) * 512;
    #pragma unroll
    for (int ni = 0; ni < 32; ++ni) {
        #pragma unroll
        for (int r = 0; r < 4; ++r) {
            outb[(size_t)(qd * 4 + r) * 512 + ni * 16 + ln] = acc[ni][r];
        }
    }
}

extern "C" void kernel_launch(void* const* d_in, const int* in_sizes, int n_in,
                              void* d_out, int out_size, void* d_ws, size_t ws_size,
                              hipStream_t stream) {
    const float* q  = (const float*)d_in[0];
    const float* k  = (const float*)d_in[1];
    const float* v  = (const float*)d_in[2];
    const float* wq = (const float*)d_in[3];
    const float* wk = (const float*)d_in[4];
    const float* wv = (const float*)d_in[5];

    // workspace layout (bf16 projections + row sums): ~96.1 MiB total
    unsigned short* qp  = (unsigned short*)d_ws;
    unsigned short* kp  = qp + (size_t)32768 * 512;
    unsigned short* vpT = kp + (size_t)32768 * 512;
    float* lsum = (float*)(vpT + (size_t)16 * 512 * 2048);

    float* out  = (float*)d_out;                 // [16,2048,512]
    float* attn = out + ATTN_OFF;                // [16,2048,2048]

    hipMemsetAsync(lsum, 0, (size_t)16 * 2048 * sizeof(float), stream);

    proj_kernel<<<dim3(256, 4, 3), 256, 0, stream>>>(q, k, v, wq, wk, wv, qp, kp, vpT);
    dots_kernel<<<dim3(16, 16, 16), 256, 0, stream>>>(qp, kp, attn, lsum);
    out_kernel<<<dim3(16, 16), 512, 0, stream>>>(vpT, attn, lsum, out);
}